// Round 1
// baseline (343.958 us; speedup 1.0000x reference)
//
#include <hip/hip_runtime.h>
#include <math.h>

#define N_NODES 50000

// ---------------- degree histogram ----------------
__global__ void count_kernel(const int* __restrict__ dst, int E, int* __restrict__ counts) {
    int i = blockIdx.x * blockDim.x + threadIdx.x;
    if (i < E) atomicAdd(&counts[dst[i]], 1);
}

// ---------------- block-level exclusive scan (Hillis-Steele) ----------------
// outEx[i] = exclusive prefix within block; blocksum[b] = block total (if non-null).
// Safe to call in-place (in == outEx).
__global__ void scan_block_kernel(const int* __restrict__ in, int n,
                                  int* __restrict__ outEx, int* __restrict__ blocksum) {
    __shared__ int s[256];
    int t = threadIdx.x, i = blockIdx.x * 256 + t;
    int v = (i < n) ? in[i] : 0;
    s[t] = v;
    __syncthreads();
    for (int off = 1; off < 256; off <<= 1) {
        int x = (t >= off) ? s[t - off] : 0;
        __syncthreads();
        s[t] += x;
        __syncthreads();
    }
    if (i < n) outEx[i] = s[t] - v;
    if (t == 255 && blocksum) blocksum[blockIdx.x] = s[255];
}

// row_ptr[i] += blockoffset; cursor=row_ptr copy; dinv = rsqrt(deg) with self-loop.
__global__ void finalize_kernel(const int* __restrict__ counts, const int* __restrict__ blocksum,
                                int n, int E, int* __restrict__ row_ptr,
                                int* __restrict__ cursor, float* __restrict__ dinv) {
    int i = blockIdx.x * blockDim.x + threadIdx.x;
    if (i < n) {
        int rp = row_ptr[i] + blocksum[i >> 8];
        row_ptr[i] = rp;
        cursor[i]  = rp;
        dinv[i] = rsqrtf((float)(counts[i] + 1));   // +1 self-loop; deg>=1 so no eps needed
        if (i == 0) row_ptr[n] = E;
    }
}

// scatter edges into CSR; precompute per-edge norm = dinv[src]*dinv[dst]
__global__ void fill_kernel(const int* __restrict__ src, const int* __restrict__ dst, int E,
                            int* __restrict__ cursor, const float* __restrict__ dinv,
                            int* __restrict__ col, float* __restrict__ nrm) {
    int i = blockIdx.x * blockDim.x + threadIdx.x;
    if (i < E) {
        int s = src[i], d = dst[i];
        int p = atomicAdd(&cursor[d], 1);
        col[p] = s;
        nrm[p] = dinv[s] * dinv[d];
    }
}

// ---------------- fp32 GEMM: C[n,DOUT] = A[n,DIN] @ W[DIN,DOUT] ----------------
// 4x4 register blocking; W fully LDS-resident; A tile staged transposed in LDS.
template<int DIN, int DOUT, int BM, int KC>
__global__ __launch_bounds__(256) void gemm_kernel(const float* __restrict__ A,
                                                   const float* __restrict__ W,
                                                   float* __restrict__ C, int n) {
    constexpr int NCG = DOUT / 4;        // col groups of 4
    constexpr int NRG = BM / 4;          // row groups of 4
    static_assert(NCG * NRG == 256, "thread mapping");
    constexpr int KG = KC / 4;           // float4 groups along k in staging
    constexpr int RSTEP = 256 / KG;
    __shared__ __align__(16) float ws[DIN * DOUT];
    __shared__ __align__(16) float xs[KC][BM + 4];   // +4 pad: keeps 16B align, spreads banks
    const int t = threadIdx.x;
    for (int i = 4 * t; i < DIN * DOUT; i += 1024)
        *(float4*)&ws[i] = *(const float4*)&W[i];
    const int rowbase = blockIdx.x * BM;
    const int r0 = (t / NCG) * 4;
    const int c0 = (t % NCG) * 4;
    const int lk = (t % KG) * 4;
    const int lr = t / KG;
    float acc[4][4] = {};
    for (int kc = 0; kc < DIN; kc += KC) {
        __syncthreads();
        #pragma unroll
        for (int r = lr; r < BM; r += RSTEP) {
            int row = rowbase + r;
            if (row >= n) row = n - 1;                 // clamp: junk rows masked at store
            float4 v = *(const float4*)&A[(size_t)row * DIN + kc + lk];
            xs[lk + 0][r] = v.x; xs[lk + 1][r] = v.y;
            xs[lk + 2][r] = v.z; xs[lk + 3][r] = v.w;
        }
        __syncthreads();
        #pragma unroll
        for (int k = 0; k < KC; ++k) {
            float ar[4], wr[4];
            *(float4*)ar = *(const float4*)&xs[k][r0];
            *(float4*)wr = *(const float4*)&ws[(kc + k) * DOUT + c0];
            #pragma unroll
            for (int i = 0; i < 4; ++i)
                #pragma unroll
                for (int j = 0; j < 4; ++j)
                    acc[i][j] += ar[i] * wr[j];
        }
    }
    #pragma unroll
    for (int i = 0; i < 4; ++i) {
        int row = rowbase + r0 + i;
        if (row < n) {
            float4 v = make_float4(acc[i][0], acc[i][1], acc[i][2], acc[i][3]);
            *(float4*)&C[(size_t)row * DOUT + c0] = v;
        }
    }
}

// ---------------- layer-1 aggregation: one wave per node, lane = feature (D=64) ----------------
// out[n][f] = relu(b1[f] + dinv[n]^2*XW[n][f] + sum_e nrm[e]*XW[col[e]][f])
__global__ void gather64_kernel(const float* __restrict__ XW, const int* __restrict__ row_ptr,
                                const int* __restrict__ col, const float* __restrict__ nrm,
                                const float* __restrict__ dinv, const float* __restrict__ bias,
                                float* __restrict__ out, int n) {
    int gid = blockIdx.x * blockDim.x + threadIdx.x;
    int node = gid >> 6;
    int f = gid & 63;
    if (node >= n) return;
    float dv = dinv[node];
    float acc = dv * dv * XW[(size_t)node * 64 + f];
    int e = row_ptr[node], end = row_ptr[node + 1];
    for (; e < end; ++e) {
        int s = col[e];
        float w = nrm[e];
        acc += w * XW[(size_t)s * 64 + f];
    }
    acc += bias[f];
    out[(size_t)node * 64 + f] = fmaxf(acc, 0.f);
}

// ---------------- layer-2 aggregation + attention epilogue (D=32) ----------------
// wave per node; lanes split: f = lane&31, half = lane>>5 processes alternate edges.
__global__ void gather32_final_kernel(const float* __restrict__ XW, const int* __restrict__ row_ptr,
                                      const int* __restrict__ col, const float* __restrict__ nrm,
                                      const float* __restrict__ dinv, const float* __restrict__ bias,
                                      const float* __restrict__ aw, const float* __restrict__ ab,
                                      float* __restrict__ out, int n) {
    int gid = blockIdx.x * blockDim.x + threadIdx.x;
    int node = gid >> 6;
    int lane = threadIdx.x & 63;
    int f = lane & 31, half = lane >> 5;
    if (node >= n) return;
    float acc = 0.f;
    if (half == 0) {
        float dv = dinv[node];
        acc = dv * dv * XW[(size_t)node * 32 + f];
    }
    int start = row_ptr[node], end = row_ptr[node + 1];
    for (int e = start + half; e < end; e += 2) {
        int s = col[e];
        float w = nrm[e];
        acc += w * XW[(size_t)s * 32 + f];
    }
    acc += __shfl_xor(acc, 32, 64);                 // combine the two edge halves
    float h = fmaxf(acc + bias[f], 0.f);
    float sca = h * aw[f];
    #pragma unroll
    for (int m = 16; m >= 1; m >>= 1) sca += __shfl_xor(sca, m, 64);  // reduce over 32 features
    float attn = 1.f / (1.f + __expf(-sca));
    if (half == 0) out[(size_t)node * 32 + f] = h * attn;
}

extern "C" void kernel_launch(void* const* d_in, const int* in_sizes, int n_in,
                              void* d_out, int out_size, void* d_ws, size_t ws_size,
                              hipStream_t stream) {
    const float* x  = (const float*)d_in[0];
    const int*   ei = (const int*)d_in[1];
    const float* W1 = (const float*)d_in[2];
    const float* b1 = (const float*)d_in[3];
    const float* W2 = (const float*)d_in[4];
    const float* b2 = (const float*)d_in[5];
    const float* aw = (const float*)d_in[6];
    const float* ab = (const float*)d_in[7];
    float* out = (float*)d_out;

    const int n = N_NODES;
    const int E = in_sizes[1] / 2;
    const int* src = ei;
    const int* dst = ei + E;

    // workspace carve-up (256B aligned)
    char* w = (char*)d_ws;
    auto alloc = [&](size_t bytes) { char* p = w; w += (bytes + 255) & ~(size_t)255; return p; };
    int*   counts   = (int*)  alloc((size_t)n * 4);
    int*   row_ptr  = (int*)  alloc((size_t)(n + 1) * 4);
    int*   cursor   = (int*)  alloc((size_t)n * 4);
    int*   blocksum = (int*)  alloc(1024);
    float* dinv     = (float*)alloc((size_t)n * 4);
    int*   col      = (int*)  alloc((size_t)E * 4);
    float* nrm      = (float*)alloc((size_t)E * 4);
    float* bufA     = (float*)alloc((size_t)n * 64 * 4);   // XW1, later XW2
    float* bufB     = (float*)alloc((size_t)n * 64 * 4);   // h1

    const int nb = (n + 255) / 256;   // 196 scan blocks

    hipMemsetAsync(counts, 0, (size_t)n * 4, stream);
    count_kernel<<<(E + 255) / 256, 256, 0, stream>>>(dst, E, counts);
    scan_block_kernel<<<nb, 256, 0, stream>>>(counts, n, row_ptr, blocksum);
    scan_block_kernel<<<1, 256, 0, stream>>>(blocksum, nb, blocksum, nullptr);
    finalize_kernel<<<nb, 256, 0, stream>>>(counts, blocksum, n, E, row_ptr, cursor, dinv);
    fill_kernel<<<(E + 255) / 256, 256, 0, stream>>>(src, dst, E, cursor, dinv, col, nrm);

    gemm_kernel<128, 64, 64, 32><<<(n + 63) / 64, 256, 0, stream>>>(x, W1, bufA, n);
    gather64_kernel<<<((size_t)n * 64 + 255) / 256, 256, 0, stream>>>(
        bufA, row_ptr, col, nrm, dinv, b1, bufB, n);
    gemm_kernel<64, 32, 128, 32><<<(n + 127) / 128, 256, 0, stream>>>(bufB, W2, bufA, n);
    gather32_final_kernel<<<((size_t)n * 64 + 255) / 256, 256, 0, stream>>>(
        bufA, row_ptr, col, nrm, dinv, b2, aw, ab, out, n);
}

// Round 2
// 265.668 us; speedup vs baseline: 1.2947x; 1.2947x over previous
//
#include <hip/hip_runtime.h>
#include <math.h>

#define N_NODES 50000

// ---------------- degree histogram ----------------
__global__ void count_kernel(const int* __restrict__ dst, int E, int* __restrict__ counts) {
    int i = blockIdx.x * blockDim.x + threadIdx.x;
    if (i < E) atomicAdd(&counts[dst[i]], 1);
}

// ---------------- block-level exclusive scan (Hillis-Steele) ----------------
__global__ void scan_block_kernel(const int* __restrict__ in, int n,
                                  int* __restrict__ outEx, int* __restrict__ blocksum) {
    __shared__ int s[256];
    int t = threadIdx.x, i = blockIdx.x * 256 + t;
    int v = (i < n) ? in[i] : 0;
    s[t] = v;
    __syncthreads();
    for (int off = 1; off < 256; off <<= 1) {
        int x = (t >= off) ? s[t - off] : 0;
        __syncthreads();
        s[t] += x;
        __syncthreads();
    }
    if (i < n) outEx[i] = s[t] - v;
    if (t == 255 && blocksum) blocksum[blockIdx.x] = s[255];
}

__global__ void finalize_kernel(const int* __restrict__ counts, const int* __restrict__ blocksum,
                                int n, int E, int* __restrict__ row_ptr,
                                int* __restrict__ cursor, float* __restrict__ dinv) {
    int i = blockIdx.x * blockDim.x + threadIdx.x;
    if (i < n) {
        int rp = row_ptr[i] + blocksum[i >> 8];
        row_ptr[i] = rp;
        cursor[i]  = rp;
        dinv[i] = rsqrtf((float)(counts[i] + 1));   // +1 self-loop
        if (i == 0) row_ptr[n] = E;
    }
}

// scatter edges into CSR as packed records {col, norm}
__global__ void fill_kernel(const int* __restrict__ src, const int* __restrict__ dst, int E,
                            int* __restrict__ cursor, const float* __restrict__ dinv,
                            int2* __restrict__ edges) {
    int i = blockIdx.x * blockDim.x + threadIdx.x;
    if (i < E) {
        int s = src[i], d = dst[i];
        int p = atomicAdd(&cursor[d], 1);
        edges[p] = make_int2(s, __float_as_int(dinv[s] * dinv[d]));
    }
}

// ---------------- fp32 GEMM: C[n,DOUT] = A[n,DIN] @ W[DIN,DOUT] ----------------
template<int DIN, int DOUT, int BM, int KC>
__global__ __launch_bounds__(256) void gemm_kernel(const float* __restrict__ A,
                                                   const float* __restrict__ W,
                                                   float* __restrict__ C, int n) {
    constexpr int NCG = DOUT / 4;
    constexpr int NRG = BM / 4;
    static_assert(NCG * NRG == 256, "thread mapping");
    constexpr int KG = KC / 4;
    constexpr int RSTEP = 256 / KG;
    __shared__ __align__(16) float ws[DIN * DOUT];
    __shared__ __align__(16) float xs[KC][BM + 4];
    const int t = threadIdx.x;
    for (int i = 4 * t; i < DIN * DOUT; i += 1024)
        *(float4*)&ws[i] = *(const float4*)&W[i];
    const int rowbase = blockIdx.x * BM;
    const int r0 = (t / NCG) * 4;
    const int c0 = (t % NCG) * 4;
    const int lk = (t % KG) * 4;
    const int lr = t / KG;
    float acc[4][4] = {};
    for (int kc = 0; kc < DIN; kc += KC) {
        __syncthreads();
        #pragma unroll
        for (int r = lr; r < BM; r += RSTEP) {
            int row = rowbase + r;
            if (row >= n) row = n - 1;
            float4 v = *(const float4*)&A[(size_t)row * DIN + kc + lk];
            xs[lk + 0][r] = v.x; xs[lk + 1][r] = v.y;
            xs[lk + 2][r] = v.z; xs[lk + 3][r] = v.w;
        }
        __syncthreads();
        #pragma unroll
        for (int k = 0; k < KC; ++k) {
            float ar[4], wr[4];
            *(float4*)ar = *(const float4*)&xs[k][r0];
            *(float4*)wr = *(const float4*)&ws[(kc + k) * DOUT + c0];
            #pragma unroll
            for (int i = 0; i < 4; ++i)
                #pragma unroll
                for (int j = 0; j < 4; ++j)
                    acc[i][j] += ar[i] * wr[j];
        }
    }
    #pragma unroll
    for (int i = 0; i < 4; ++i) {
        int row = rowbase + r0 + i;
        if (row < n) {
            float4 v = make_float4(acc[i][0], acc[i][1], acc[i][2], acc[i][3]);
            *(float4*)&C[(size_t)row * DOUT + c0] = v;
        }
    }
}

// ---------------- layer-1 gather (D=64) fused with GEMM2 (64->32) ----------------
// h[node][f] = relu(b1[f] + dinv^2*XW[node][f] + sum_e w_e*XW[col_e][f])   (f = lane)
// out[node][j] = sum_f h[f] * W2[f][j]      (in-wave via shfl; W2 in LDS)
__global__ __launch_bounds__(256) void gather64_fuse_kernel(
        const float* __restrict__ XW, const int* __restrict__ row_ptr,
        const int2* __restrict__ edges, const float* __restrict__ dinv,
        const float* __restrict__ b1, const float* __restrict__ W2,
        float* __restrict__ out, int n) {
    __shared__ __align__(16) float ws2[64 * 32];
    const int t = threadIdx.x;
    for (int i = 4 * t; i < 64 * 32; i += 1024)
        *(float4*)&ws2[i] = *(const float4*)&W2[i];
    __syncthreads();
    int gid = blockIdx.x * blockDim.x + t;
    int node = gid >> 6;
    int f = t & 63;
    if (node < n) {
        float dv = dinv[node];
        float acc = dv * dv * XW[(size_t)node * 64 + f];
        int e = row_ptr[node], end = row_ptr[node + 1];
        // 8-wide: 8 independent XW loads in flight per round trip
        for (; e + 8 <= end; e += 8) {
            int2 p0 = edges[e+0], p1 = edges[e+1], p2 = edges[e+2], p3 = edges[e+3];
            int2 p4 = edges[e+4], p5 = edges[e+5], p6 = edges[e+6], p7 = edges[e+7];
            float v0 = XW[(size_t)p0.x * 64 + f], v1 = XW[(size_t)p1.x * 64 + f];
            float v2 = XW[(size_t)p2.x * 64 + f], v3 = XW[(size_t)p3.x * 64 + f];
            float v4 = XW[(size_t)p4.x * 64 + f], v5 = XW[(size_t)p5.x * 64 + f];
            float v6 = XW[(size_t)p6.x * 64 + f], v7 = XW[(size_t)p7.x * 64 + f];
            acc += __int_as_float(p0.y) * v0; acc += __int_as_float(p1.y) * v1;
            acc += __int_as_float(p2.y) * v2; acc += __int_as_float(p3.y) * v3;
            acc += __int_as_float(p4.y) * v4; acc += __int_as_float(p5.y) * v5;
            acc += __int_as_float(p6.y) * v6; acc += __int_as_float(p7.y) * v7;
        }
        if (e + 4 <= end) {
            int2 p0 = edges[e+0], p1 = edges[e+1], p2 = edges[e+2], p3 = edges[e+3];
            float v0 = XW[(size_t)p0.x * 64 + f], v1 = XW[(size_t)p1.x * 64 + f];
            float v2 = XW[(size_t)p2.x * 64 + f], v3 = XW[(size_t)p3.x * 64 + f];
            acc += __int_as_float(p0.y) * v0; acc += __int_as_float(p1.y) * v1;
            acc += __int_as_float(p2.y) * v2; acc += __int_as_float(p3.y) * v3;
            e += 4;
        }
        for (; e < end; ++e) {
            int2 p = edges[e];
            acc += __int_as_float(p.y) * XW[(size_t)p.x * 64 + f];
        }
        float h = fmaxf(acc + b1[f], 0.f);
        // fused GEMM2: y_j = sum_f h_f * W2[f][j]; halves split the f-range
        int j = f & 31, half = f >> 5;
        int fbase = half << 5;
        float y = 0.f;
        #pragma unroll
        for (int k = 0; k < 32; ++k) {
            float hf = __shfl(h, fbase + k, 64);
            y += hf * ws2[(fbase + k) * 32 + j];
        }
        y += __shfl_xor(y, 32, 64);
        if (half == 0) out[(size_t)node * 32 + j] = y;
    }
}

// ---------------- layer-2 gather (D=32) + attention epilogue ----------------
__global__ __launch_bounds__(256) void gather32_final_kernel(
        const float* __restrict__ XW, const int* __restrict__ row_ptr,
        const int2* __restrict__ edges, const float* __restrict__ dinv,
        const float* __restrict__ bias, const float* __restrict__ aw,
        const float* __restrict__ ab, float* __restrict__ out, int n) {
    int gid = blockIdx.x * blockDim.x + threadIdx.x;
    int node = gid >> 6;
    int lane = threadIdx.x & 63;
    int f = lane & 31, half = lane >> 5;
    if (node >= n) return;
    float acc = 0.f;
    if (half == 0) {
        float dv = dinv[node];
        acc = dv * dv * XW[(size_t)node * 32 + f];
    }
    int end = row_ptr[node + 1];
    int e = row_ptr[node] + half;     // halves take alternate edges
    for (; e + 6 < end; e += 8) {     // 4 per half in flight
        int2 p0 = edges[e+0], p1 = edges[e+2], p2 = edges[e+4], p3 = edges[e+6];
        float v0 = XW[(size_t)p0.x * 32 + f], v1 = XW[(size_t)p1.x * 32 + f];
        float v2 = XW[(size_t)p2.x * 32 + f], v3 = XW[(size_t)p3.x * 32 + f];
        acc += __int_as_float(p0.y) * v0; acc += __int_as_float(p1.y) * v1;
        acc += __int_as_float(p2.y) * v2; acc += __int_as_float(p3.y) * v3;
    }
    for (; e < end; e += 2) {
        int2 p = edges[e];
        acc += __int_as_float(p.y) * XW[(size_t)p.x * 32 + f];
    }
    acc += __shfl_xor(acc, 32, 64);                 // combine halves
    float h = fmaxf(acc + bias[f], 0.f);
    float sca = h * aw[f];
    #pragma unroll
    for (int m = 16; m >= 1; m >>= 1) sca += __shfl_xor(sca, m, 64);
    float attn = 1.f / (1.f + __expf(-(sca + ab[0])));
    if (half == 0) out[(size_t)node * 32 + f] = h * attn;
}

extern "C" void kernel_launch(void* const* d_in, const int* in_sizes, int n_in,
                              void* d_out, int out_size, void* d_ws, size_t ws_size,
                              hipStream_t stream) {
    const float* x  = (const float*)d_in[0];
    const int*   ei = (const int*)d_in[1];
    const float* W1 = (const float*)d_in[2];
    const float* b1 = (const float*)d_in[3];
    const float* W2 = (const float*)d_in[4];
    const float* b2 = (const float*)d_in[5];
    const float* aw = (const float*)d_in[6];
    const float* ab = (const float*)d_in[7];
    float* out = (float*)d_out;

    const int n = N_NODES;
    const int E = in_sizes[1] / 2;
    const int* src = ei;
    const int* dst = ei + E;

    char* w = (char*)d_ws;
    auto alloc = [&](size_t bytes) { char* p = w; w += (bytes + 255) & ~(size_t)255; return p; };
    int*   counts   = (int*)  alloc((size_t)n * 4);
    int*   row_ptr  = (int*)  alloc((size_t)(n + 1) * 4);
    int*   cursor   = (int*)  alloc((size_t)n * 4);
    int*   blocksum = (int*)  alloc(1024);
    float* dinv     = (float*)alloc((size_t)n * 4);
    int2*  edges    = (int2*) alloc((size_t)E * 8);
    float* bufA     = (float*)alloc((size_t)n * 64 * 4);   // XW1
    float* bufB     = (float*)alloc((size_t)n * 32 * 4);   // XW2 (= h1 @ W2)

    const int nb = (n + 255) / 256;

    hipMemsetAsync(counts, 0, (size_t)n * 4, stream);
    count_kernel<<<(E + 255) / 256, 256, 0, stream>>>(dst, E, counts);
    scan_block_kernel<<<nb, 256, 0, stream>>>(counts, n, row_ptr, blocksum);
    scan_block_kernel<<<1, 256, 0, stream>>>(blocksum, nb, blocksum, nullptr);
    finalize_kernel<<<nb, 256, 0, stream>>>(counts, blocksum, n, E, row_ptr, cursor, dinv);
    fill_kernel<<<(E + 255) / 256, 256, 0, stream>>>(src, dst, E, cursor, dinv, edges);

    gemm_kernel<128, 64, 64, 32><<<(n + 63) / 64, 256, 0, stream>>>(x, W1, bufA, n);
    gather64_fuse_kernel<<<((size_t)n * 64 + 255) / 256, 256, 0, stream>>>(
        bufA, row_ptr, edges, dinv, b1, W2, bufB, n);
    gather32_final_kernel<<<((size_t)n * 64 + 255) / 256, 256, 0, stream>>>(
        bufB, row_ptr, edges, dinv, b2, aw, ab, out, n);
}